// Round 1
// 156.627 us; speedup vs baseline: 1.0489x; 1.0489x over previous
//
#include <hip/hip_runtime.h>

typedef __attribute__((ext_vector_type(8))) short short8;
typedef __attribute__((ext_vector_type(4))) float floatx4;

#define NLEV 5
#define B_   16
#define S_   4096
#define D_   128
#define P_   4096
#define CTOT 496                 // 16+32+64+128+256
#define BP   (B_ * CTOT)
#define WPADG 512                // padded wave count for decoder K
#define CENC 1488                // total encoder columns (sum 3n)
#define INV2PI 0.15915494309189535f
#define NJBLK 336                // balanced encoder job-blocks per b

// round-to-nearest-even float -> bf16
__device__ __forceinline__ unsigned short f2bf(float f) {
    unsigned u = __float_as_uint(f);
    u += 0x7fffu + ((u >> 16) & 1u);
    return (unsigned short)(u >> 16);
}
__device__ __forceinline__ unsigned int pack2(float a, float b) {
    return (unsigned int)f2bf(a) | ((unsigned int)f2bf(b) << 16);
}

// ---------------------------------------------------------------------------
// Pack weights to bf16 AND zero the accumulator (memset dispatch folded in):
//   wencb[c][d]  c in level-concat order (1488 x 128)
//   wdbT [d][w]  (128 x 512, w zero-padded 496->512)
// ---------------------------------------------------------------------------
__global__ void pack_weights(const float* __restrict__ we0, const float* __restrict__ we1,
                             const float* __restrict__ we2, const float* __restrict__ we3,
                             const float* __restrict__ we4,
                             const float* __restrict__ wd0, const float* __restrict__ wd1,
                             const float* __restrict__ wd2, const float* __restrict__ wd3,
                             const float* __restrict__ wd4,
                             unsigned short* __restrict__ wencb,
                             unsigned short* __restrict__ wdbT,
                             float* __restrict__ accb)
{
    int idx = blockIdx.x * 256 + threadIdx.x;
    if (idx < 3 * BP) accb[idx] = 0.0f;      // folded memset (23808 floats)
    const int NE = CENC * D_;                 // 190464
    if (idx < NE) {
        int c = idx >> 7, d = idx & 127;
        const float* src; int off;
        if (c < 48)        { src = we0; off = 0;   }
        else if (c < 144)  { src = we1; off = 48;  }
        else if (c < 336)  { src = we2; off = 144; }
        else               { src = (c < 720) ? we3 : we4; off = (c < 720) ? 336 : 720; }
        wencb[idx] = f2bf(src[(size_t)(c - off) * D_ + d]);
    } else {
        int k = idx - NE;
        if (k >= D_ * WPADG) return;
        int d = k >> 9, w = k & 511;
        float v = 0.0f;
        if (w < CTOT) {
            const float* src; int off, nl;
            if (w < 16)       { src = wd0; off = 0;   nl = 16;  }
            else if (w < 48)  { src = wd1; off = 16;  nl = 32;  }
            else if (w < 112) { src = wd2; off = 48;  nl = 64;  }
            else if (w < 240) { src = wd3; off = 112; nl = 128; }
            else              { src = wd4; off = 240; nl = 256; }
            v = src[(size_t)d * nl + (w - off)];
        }
        wdbT[k] = f2bf(v);
    }
}

// ---------------------------------------------------------------------------
// Balanced fused encoder. Job = (t-tile bx, level l, 16-col chunk ci).
// Per b: chunks(bx) = 9 + [bx<16]*12 + [bx<8]*24 + [bx<4]*48 (levels with
// 64*(bx+1) <= seff participate; t0 = S - 64*(bx+1)). Blocks carry 4 chunks
// (1/wave): 24,12,6,3 blocks per bx -> 336 uniform blocks per b.
// C layout (verified): col = lane&15 = c, row = quad*4+reg = t.
// Epilogue EMA weight factorized: wt = C0 * fs^(16m) * fs^(4*quad+r)
// (4 v_exp_f32 per wave instead of 16; identical up to 1-ulp fp32).
// ---------------------------------------------------------------------------
__global__ __launch_bounds__(256) void encoder(
    const float* __restrict__ kv, const int* __restrict__ positions,
    const unsigned short* __restrict__ wencb,
    const float* __restrict__ bfr0, const float* __restrict__ bfr1,
    const float* __restrict__ bfr2, const float* __restrict__ bfr3,
    const float* __restrict__ bfr4,
    float* __restrict__ accb)
{
    __shared__ unsigned short kvb[64 * 136];   // [t][d] bf16, stride 136
    __shared__ float pf[64];
    const int b   = blockIdx.y;
    const int bid = blockIdx.x;
    const int tid = threadIdx.x;

    // decode (bx, local block) from balanced prefix
    int bx, lb;
    if (bid < 96)       { bx = bid / 24;            lb = bid % 24; }
    else if (bid < 144) { int r = bid - 96;  bx = 4 + r / 12; lb = r % 12; }
    else if (bid < 192) { int r = bid - 144; bx = 8 + r / 6;  lb = r % 6;  }
    else                { int r = bid - 192; bx = 16 + r / 3; lb = r % 3;  }
    const int t0 = S_ - 64 * (bx + 1);

    // stage kv tile: fp32 float4 -> bf16 LDS
    const float* src = kv + ((size_t)(b * S_ + t0)) * D_;
    #pragma unroll
    for (int f = 0; f < 8; ++f) {
        int idx = f * 256 + tid;
        int t = idx >> 5, d4 = idx & 31;
        float4 val = *(const float4*)(src + t * D_ + d4 * 4);
        unsigned long long u = (unsigned long long)pack2(val.x, val.y)
                             | ((unsigned long long)pack2(val.z, val.w) << 32);
        *(unsigned long long*)&kvb[t * 136 + d4 * 4] = u;
    }
    if (tid < 64) pf[tid] = (float)positions[t0 + tid] * (1.0f / 8192.0f);
    __syncthreads();

    const int wid = tid >> 6, lane = tid & 63, ln = lane & 15, quad = lane >> 4;

    // wave's job id -> (level, chunk)
    const int cnt = 9 + (bx < 16 ? 12 : 0) + (bx < 8 ? 24 : 0) + (bx < 4 ? 48 : 0);
    int jid = lb * 4 + wid;
    if (jid >= cnt) return;    // no barriers past this point

    const int   n_l[5]  = {16, 32, 64, 128, 256};
    const int   coff[5] = {0, 16, 48, 112, 240};
    const int   c3[5]   = {0, 48, 144, 336, 720};
    const float al[5]   = {0.001f, 0.005f, 0.02f, 0.05f, 0.1f};
    const float l2m[5]  = {-0.0014434169f, -0.0072315692f, -0.0291463449f,
                           -0.0740005794f, -0.1520030934f};
    const float* bfp[5] = {bfr0, bfr1, bfr2, bfr3, bfr4};

    int l = 0, ci = jid;
    {
        const int sz[5] = {3, 6, (bx < 16 ? 12 : 0), (bx < 8 ? 24 : 0), (bx < 4 ? 48 : 0)};
        #pragma unroll
        for (int q = 0; q < 4; ++q) {
            if (ci >= sz[l]) { ci -= sz[l]; ++l; }
        }
    }
    const int n = n_l[l];

    // GEMM: 64 t-rows x 16 cols -> acc[m] over 4 m-tiles, K = 128 (4 ksteps)
    const unsigned short* wrow = wencb + (size_t)(c3[l] + ci * 16 + ln) * D_;
    floatx4 acc[4];
    #pragma unroll
    for (int m = 0; m < 4; ++m) acc[m] = (floatx4){0.f, 0.f, 0.f, 0.f};
    #pragma unroll
    for (int k = 0; k < 4; ++k) {
        short8 bfg = *(const short8*)(wrow + k * 32 + quad * 8);
        #pragma unroll
        for (int m = 0; m < 4; ++m) {
            short8 af = *(const short8*)&kvb[(m * 16 + ln) * 136 + k * 32 + quad * 8];
            acc[m] = __builtin_amdgcn_mfma_f32_16x16x32_bf16(af, bfg, acc[m], 0, 0, 0);
        }
    }

    // epilogue: EMA weight + kind transform, quad-reduce, atomic
    const int kind  = (ci * 16) / n;
    const int local = ci * 16 + ln - kind * n;
    const float bsv = (kind == 0) ? bfp[l][local] : 0.0f;

    const float l2 = l2m[l];
    const float fs = exp2f(-l2);                          // per +1 t step
    const float fq = exp2f(-(float)(quad * 4) * l2);      // per-lane quad offset
    const float em = exp2f(-16.0f * l2);                  // per m-tile step
    float fr[4];
    fr[0] = fq; fr[1] = fq * fs; fr[2] = fr[1] * fs; fr[3] = fr[2] * fs;
    float Cm = al[l] * exp2f((float)(S_ - 1 - t0) * l2);  // weight at trel=0

    float s = 0.0f;
    #pragma unroll
    for (int m = 0; m < 4; ++m) {
        #pragma unroll
        for (int r = 0; r < 4; ++r) {
            int   trel = m * 16 + quad * 4 + r;
            float wt   = Cm * fr[r];
            float v    = acc[m][r];
            if (kind == 0) {
                float rev = bsv * pf[trel];     // sin(2pi * base * pos/8192)
                rev = __builtin_amdgcn_fractf(rev);
                v *= __builtin_amdgcn_sinf(rev);
            } else if (kind == 1) {
                v = fabsf(v);
            }
            s += wt * v;
        }
        Cm *= em;
    }
    s += __shfl_xor(s, 16);
    s += __shfl_xor(s, 32);
    if (lane < 16)
        atomicAdd(accb + (size_t)kind * BP + b * CTOT + coff[l] + local, s);
}

// ---------------------------------------------------------------------------
// Decoder: out[b,p,:] = sum_w A*sin(2pi*rev) * wd[w,:] via bf16 MFMA.
// Block 64p x 128d; K=512 split into 2 passes of 256 -> v[64][264] bf16
// (34 KB LDS, 4 blocks/CU). 4 waves split over d.
// Combine folded in: params derived from accb + base_freqs per half
// (former combine kernel deleted; saves a dispatch).
// Sin table: v_fract + 2-wide v_cvt_pk_bf16_f32 pack (RNE, bit-identical
// to manual f2bf).
// ---------------------------------------------------------------------------
__global__ __launch_bounds__(256) void decoder(
    const float* __restrict__ accb,
    const unsigned short* __restrict__ wdbT, const int* __restrict__ rpos,
    const float* __restrict__ b0, const float* __restrict__ b1,
    const float* __restrict__ b2, const float* __restrict__ b3,
    const float* __restrict__ b4,
    float* __restrict__ out)
{
    __shared__ unsigned short v[64 * 264];
    __shared__ float rpn[64];
    const int b = blockIdx.y, p0 = blockIdx.x * 64, tid = threadIdx.x;
    if (tid < 64) rpn[tid] = (float)rpos[p0 + tid] * (1.0f / 8192.0f);

    const int wid = tid >> 6, lane = tid & 63, ln = lane & 15, quad = lane >> 4;
    const int nt0 = wid * 2;

    floatx4 acc[4][2];
    #pragma unroll
    for (int m = 0; m < 4; ++m)
        #pragma unroll
        for (int j = 0; j < 2; ++j) acc[m][j] = (floatx4){0.f, 0.f, 0.f, 0.f};

    #pragma unroll
    for (int half = 0; half < 2; ++half) {
        const int w0 = half * 256;
        // per-thread column params (w = w0 + tid), combine math inlined
        const int w = w0 + tid;
        float A = 0.f, Q = 0.f, Ph = 0.f;
        if (w < CTOT) {
            const float* bf; int off;
            if (w < 16)       { bf = b0; off = 0;   }
            else if (w < 48)  { bf = b1; off = 16;  }
            else if (w < 112) { bf = b2; off = 48;  }
            else if (w < 240) { bf = b3; off = 112; }
            else              { bf = b4; off = 240; }
            float f  = accb[0 * BP + b * CTOT + w];
            A        = accb[1 * BP + b * CTOT + w];
            float ph = accb[2 * BP + b * CTOT + w];
            Q  = f + bf[w - off];
            Ph = ph * INV2PI;
        }
        __syncthreads();   // prior MFMA reads done (and rpn ready on pass 0)
        for (int p = 0; p < 64; p += 2) {
            float r0 = __builtin_amdgcn_fractf(fmaf(Q, rpn[p],     Ph));
            float r1 = __builtin_amdgcn_fractf(fmaf(Q, rpn[p + 1], Ph));
            float s0 = A * __builtin_amdgcn_sinf(r0);
            float s1 = A * __builtin_amdgcn_sinf(r1);
            unsigned pk;
            asm("v_cvt_pk_bf16_f32 %0, %1, %2" : "=v"(pk) : "v"(s0), "v"(s1));
            v[p * 264 + tid]       = (unsigned short)pk;
            v[(p + 1) * 264 + tid] = (unsigned short)(pk >> 16);
        }
        __syncthreads();

        #pragma unroll
        for (int kk = 0; kk < 8; ++kk) {
            short8 bn[2];
            #pragma unroll
            for (int j = 0; j < 2; ++j)
                bn[j] = *(const short8*)(wdbT + (size_t)((nt0 + j) * 16 + ln) * WPADG
                                         + w0 + kk * 32 + quad * 8);
            short8 am[4];
            #pragma unroll
            for (int m = 0; m < 4; ++m)
                am[m] = *(const short8*)&v[(m * 16 + ln) * 264 + kk * 32 + quad * 8];
            #pragma unroll
            for (int m = 0; m < 4; ++m)
                #pragma unroll
                for (int j = 0; j < 2; ++j)
                    acc[m][j] = __builtin_amdgcn_mfma_f32_16x16x32_bf16(
                                    am[m], bn[j], acc[m][j], 0, 0, 0);
        }
    }

    // store: col = lane&15 -> d, row = quad*4+reg -> p
    #pragma unroll
    for (int m = 0; m < 4; ++m)
        #pragma unroll
        for (int j = 0; j < 2; ++j)
            #pragma unroll
            for (int r = 0; r < 4; ++r) {
                int p = p0 + m * 16 + quad * 4 + r;
                int d = (nt0 + j) * 16 + ln;
                out[((size_t)(b * P_ + p)) * D_ + d] = acc[m][j][r];
            }
}

// ---------------------------------------------------------------------------
extern "C" void kernel_launch(void* const* d_in, const int* in_sizes, int n_in,
                              void* d_out, int out_size, void* d_ws, size_t ws_size,
                              hipStream_t stream)
{
    const float* kv        = (const float*)d_in[0];
    const int*   positions = (const int*)d_in[1];
    const int*   rpos      = (const int*)d_in[2];

    char* ws = (char*)d_ws;
    float*          accb  = (float*)(ws + 0);                 // 95232 B
    unsigned short* wencb = (unsigned short*)(ws + 95232);    // 380928 B
    unsigned short* wdbT  = (unsigned short*)(ws + 476160);   // 131072 B

    // 3 dispatches total (was 5: memset + 4 kernels)
    pack_weights<<<1000, 256, 0, stream>>>(
        (const float*)d_in[3], (const float*)d_in[6], (const float*)d_in[9],
        (const float*)d_in[12], (const float*)d_in[15],
        (const float*)d_in[4], (const float*)d_in[7], (const float*)d_in[10],
        (const float*)d_in[13], (const float*)d_in[16],
        wencb, wdbT, accb);

    encoder<<<dim3(NJBLK, B_), 256, 0, stream>>>(
        kv, positions, wencb,
        (const float*)d_in[5], (const float*)d_in[8], (const float*)d_in[11],
        (const float*)d_in[14], (const float*)d_in[17],
        accb);

    decoder<<<dim3(P_ / 64, B_), 256, 0, stream>>>(
        accb, wdbT, rpos,
        (const float*)d_in[5], (const float*)d_in[8], (const float*)d_in[11],
        (const float*)d_in[14], (const float*)d_in[17],
        (float*)d_out);
}